// Round 9
// baseline (182.411 us; speedup 1.0000x reference)
//
#include <hip/hip_runtime.h>
#include <hip/hip_bf16.h>

#define NN 8192
#define NTB 8            // k-tiles per block (each 256 wide)
#define WSPAN 2080       // window span in f32 (8*256 + 32)

typedef short bfrag8 __attribute__((ext_vector_type(8)));   // 8 bf16 in 4 VGPRs
typedef float floatx4 __attribute__((ext_vector_type(4)));

static __device__ __forceinline__ unsigned short f2bf(float f) {
  unsigned u = __builtin_bit_cast(unsigned, f);
  u = (u + 0x7FFFu + ((u >> 16) & 1u)) >> 16;   // RNE
  return (unsigned short)u;
}
static __device__ __forceinline__ unsigned cvt_pk_bf16(float a, float b) {
  return (unsigned)f2bf(a) | ((unsigned)f2bf(b) << 16);
}
// truncation pack (bf16): lo16 = a.hi16, hi16 = b.hi16 — 2 VALU ops
static __device__ __forceinline__ unsigned trunc_pk_bf16(float a, float b) {
  unsigned ua = __builtin_bit_cast(unsigned, a);
  unsigned ub = __builtin_bit_cast(unsigned, b);
  return (ub & 0xFFFF0000u) | (ua >> 16);
}
static __device__ __forceinline__ float elu(float v) {
  return v > 0.f ? v : expm1f(v);
}

// ---------------- prep: W1^T bf16, W2^T bf16, regu sums --------------------
__global__ void prep_kernel(const float* __restrict__ x, const float* __restrict__ W1,
                            const float* __restrict__ W2, const float* __restrict__ rlen,
                            unsigned short* __restrict__ W1T, unsigned short* __restrict__ W2T,
                            float* __restrict__ acc) {
  const int b = blockIdx.x, t = threadIdx.x;
  if (b < 128) {
    __shared__ float tile[64][65];
    const int k0 = b * 64;
#pragma unroll
    for (int it = 0; it < 16; ++it) {
      int k = it * 4 + (t >> 6);
      tile[k][t & 63] = W1[(k0 + k) * 64 + (t & 63)];
    }
    __syncthreads();
#pragma unroll
    for (int it = 0; it < 16; ++it) {
      int f = it * 4 + (t >> 6);
      int kk = t & 63;
      W1T[f * NN + k0 + kk] = f2bf(tile[kk][f]);
    }
  } else if (b == 128) {
    for (int idx = t; idx < 64 * 64; idx += 256) {
      int k = idx >> 6, f = idx & 63;
      W2T[f * 64 + k] = f2bf(W2[idx]);
    }
  } else {
    float rl = rlen[0];
    float inv = 1.f / (2.f * rl * rl);
    int base = (b - 129) * 4096;
    float s1 = 0.f, s2 = 0.f;
    for (int ii = 0; ii < 16; ++ii) {
      int i = base + ii * 256 + t;
      float a0 = x[i], a1 = x[NN + i], a2 = x[2 * NN + i];
      float s = a0 * a0 + a1 * a1 + a2 * a2;
      s1 += s; s2 += expf(s * inv);
    }
    for (int d = 32; d > 0; d >>= 1) { s1 += __shfl_down(s1, d); s2 += __shfl_down(s2, d); }
    __shared__ float p1[4], p2[4];
    if ((t & 63) == 0) { p1[t >> 6] = s1; p2[t >> 6] = s2; }
    __syncthreads();
    if (t == 0) {
      atomicAdd(&acc[1], p1[0] + p1[1] + p1[2] + p1[3]);
      atomicAdd(&acc[2], p2[0] + p2[1] + p2[2] + p2[3]);
    }
  }
}

// ---------------- main: barrier-free fused corr + MFMA (k-quarter) ---------
// grid 1024 = 256 i-tiles x 4 k-quarters; 256 threads = 4 waves; 4 blocks/CU.
// Window (x slice, f32) staged ONCE; k-loop has NO barriers: each wave forms
// its own corr chunks into wave-private LDS (stride 80 B, conflict-free) and
// immediately consumes them as MFMA A-fragments (same-wave lgkmcnt ordering).
__global__ __launch_bounds__(256, 4) void main_kernel(
    const float* __restrict__ x, const unsigned short* __restrict__ W1T,
    float* __restrict__ part) {
  __shared__ __align__(16) float xwin[3][WSPAN];        // 24,960 B
  __shared__ __align__(16) char crp[4][32 * 80];        // 10,240 B (wave-private)

  const int t = threadIdx.x;
  const int ib = blockIdx.x >> 2;   // i-tile
  const int qb = blockIdx.x & 3;    // k-quarter
  const int i0 = ib * 32;
  const int k0 = qb * 2048;
  const int wv = t >> 6, l = t & 63;
  const int lg = l >> 4, lr = l & 15;
  const int rg = l >> 3, cg = l & 7;   // formation: 8 rowgroups x 8 colgroups

  // ---- stage window once: xwin[c][w] = x[c, (i0+k0+w) & 8191] ----
  for (int w4 = t; w4 < WSPAN / 4; w4 += 256) {
    int wbase = w4 * 4;
    int src = (i0 + k0 + wbase) & (NN - 1);
#pragma unroll
    for (int c = 0; c < 3; ++c)
      *(float4*)&xwin[c][wbase] = *(const float4*)&x[c * NN + src];
  }

  // x row values for formation (rows rg*4 .. +4)
  float xr[3][4];
#pragma unroll
  for (int c = 0; c < 3; ++c)
#pragma unroll
    for (int r = 0; r < 4; ++r)
      xr[c][r] = x[c * NN + i0 + rg * 4 + r];

  // B row pointers: output col group n -> W1T row n*16 + lr
  const unsigned short* bp[4];
#pragma unroll
  for (int n = 0; n < 4; ++n)
    bp[n] = W1T + (n * 16 + lr) * NN + k0 + lg * 8;

  floatx4 acc[2][4];
#pragma unroll
  for (int m = 0; m < 2; ++m)
#pragma unroll
    for (int n = 0; n < 4; ++n)
      acc[m][n] = floatx4{0.f, 0.f, 0.f, 0.f};

  char* crb = &crp[wv][0];

  __syncthreads();   // window ready — the ONLY barrier before the epilogue

  for (int kt = 0; kt < NTB; ++kt) {
    const int tb = kt * 256;
#pragma unroll
    for (int s2 = 0; s2 < 2; ++s2) {
      const int cb = tb + (wv + s2 * 4) * 32;   // this wave's k-chunk base
      // ---- B fragments for this chunk (L2; issued early, hidden by form) --
      uint4 bv[4];
#pragma unroll
      for (int n = 0; n < 4; ++n) bv[n] = *(const uint4*)(bp[n] + cb);

      // ---- formation: 32x32 chunk, thread tile 4x4 (diag reuse) ----
      float acf[4][4];
#pragma unroll
      for (int r = 0; r < 4; ++r)
#pragma unroll
        for (int j = 0; j < 4; ++j) acf[r][j] = 0.f;
#pragma unroll
      for (int c = 0; c < 3; ++c) {
        const float* wp = &xwin[c][cb + rg * 4 + cg * 4];
        float4 v0 = *(const float4*)(wp);
        float4 v1 = *(const float4*)(wp + 4);
        float wf[7] = {v0.x, v0.y, v0.z, v0.w, v1.x, v1.y, v1.z};
#pragma unroll
        for (int r = 0; r < 4; ++r) {
          float xv = xr[c][r];
#pragma unroll
          for (int j = 0; j < 4; ++j) acf[r][j] = fmaf(xv, wf[r + j], acf[r][j]);
        }
      }
      // ---- write chunk to wave-private cr (row stride 80 B, no conflicts) -
#pragma unroll
      for (int r = 0; r < 4; ++r) {
        const int row = rg * 4 + r;
        uint2 q = {trunc_pk_bf16(acf[r][0], acf[r][1]),
                   trunc_pk_bf16(acf[r][2], acf[r][3])};
        *(uint2*)(crb + row * 80 + cg * 8) = q;
      }
      // ---- A fragments back (same wave: ordered by lgkmcnt, no barrier) ---
      bfrag8 a0 = __builtin_bit_cast(bfrag8, *(const uint4*)(crb + lr * 80 + lg * 16));
      bfrag8 a1 = __builtin_bit_cast(bfrag8, *(const uint4*)(crb + (16 + lr) * 80 + lg * 16));
#pragma unroll
      for (int n = 0; n < 4; ++n) {
        bfrag8 bn = __builtin_bit_cast(bfrag8, bv[n]);
        acc[0][n] = __builtin_amdgcn_mfma_f32_16x16x32_bf16(a0, bn, acc[0][n], 0, 0, 0);
        acc[1][n] = __builtin_amdgcn_mfma_f32_16x16x32_bf16(a1, bn, acc[1][n], 0, 0, 0);
      }
    }
  }

  // ---- epilogue: reduce the 4 waves' k-chunk partials, write quarter-part -
  __syncthreads();
  float* h1 = (float*)&xwin[0][0];   // [32][68], reuses dead window
  for (int q = t; q < 32 * 68; q += 256) h1[q] = 0.f;
  __syncthreads();
#pragma unroll
  for (int m = 0; m < 2; ++m)
#pragma unroll
    for (int n = 0; n < 4; ++n)
#pragma unroll
      for (int r = 0; r < 4; ++r)
        atomicAdd(&h1[(m * 16 + lg * 4 + r) * 68 + n * 16 + lr], acc[m][n][r]);
  __syncthreads();
  for (int q = t; q < 32 * 64; q += 256) {
    int row = q >> 6, col = q & 63;
    part[qb * (NN * 64) + (i0 + row) * 64 + col] = h1[row * 68 + col];
  }
}

// ---------------- tail: h1 = sum of 4 parts, elu -> @W2 -> elu -> @W3 -> sum
__global__ __launch_bounds__(256, 4) void tail_kernel(
    const float* __restrict__ part, const unsigned short* __restrict__ W2T,
    const float* __restrict__ W3, float* __restrict__ acc) {
  __shared__ float z3p[256];
  __shared__ float bsum[2];
  const int t = threadIdx.x;
  const int w4 = t >> 6, l = t & 63;
  const int lg = l >> 4, lr = l & 15;
  const int m2 = w4 & 1, np2 = w4 >> 1;
  const int i0 = blockIdx.x * 128;

  const float w3a = W3[np2 * 32 + lr];
  const float w3b = W3[np2 * 32 + 16 + lr];

#pragma unroll
  for (int rg = 0; rg < 4; ++rg) {
    const int rbase = i0 + rg * 32;
    floatx4 acc2_0 = {0.f, 0.f, 0.f, 0.f}, acc2_1 = {0.f, 0.f, 0.f, 0.f};
#pragma unroll
    for (int ks2 = 0; ks2 < 2; ++ks2) {
      const int kb = ks2 * 32 + lg * 8;
      const int row = rbase + m2 * 16 + lr;
      const float* p0 = &part[row * 64 + kb];
      const float* p1 = p0 + NN * 64;
      const float* p2 = p0 + 2 * NN * 64;
      const float* p3 = p0 + 3 * NN * 64;
      unsigned qa[4];
#pragma unroll
      for (int e = 0; e < 4; ++e) {
        float v0 = elu(p0[2 * e] + p1[2 * e] + p2[2 * e] + p3[2 * e]);
        float v1 = elu(p0[2 * e + 1] + p1[2 * e + 1] + p2[2 * e + 1] + p3[2 * e + 1]);
        qa[e] = cvt_pk_bf16(v0, v1);
      }
      uint4 qv = {qa[0], qa[1], qa[2], qa[3]};
      bfrag8 a2 = __builtin_bit_cast(bfrag8, qv);
#pragma unroll
      for (int tn = 0; tn < 2; ++tn) {
        int col2 = np2 * 32 + tn * 16 + lr;
        bfrag8 b2 = __builtin_bit_cast(bfrag8, *(const uint4*)&W2T[col2 * 64 + kb]);
        if (tn == 0)
          acc2_0 = __builtin_amdgcn_mfma_f32_16x16x32_bf16(a2, b2, acc2_0, 0, 0, 0);
        else
          acc2_1 = __builtin_amdgcn_mfma_f32_16x16x32_bf16(a2, b2, acc2_1, 0, 0, 0);
      }
    }
#pragma unroll
    for (int r = 0; r < 4; ++r) {
      float v = elu(acc2_0[r]) * w3a + elu(acc2_1[r]) * w3b;
      v += __shfl_xor(v, 1); v += __shfl_xor(v, 2);
      v += __shfl_xor(v, 4); v += __shfl_xor(v, 8);
      if (lr == 0)
        z3p[(rg * 32 + m2 * 16 + lg * 4 + r) * 2 + np2] = v;
    }
  }
  __syncthreads();
  if (t < 128) {
    float sv2 = z3p[t * 2] + z3p[t * 2 + 1];
    float z3 = elu(sv2);
    z3 += __shfl_xor(z3, 1); z3 += __shfl_xor(z3, 2); z3 += __shfl_xor(z3, 4);
    z3 += __shfl_xor(z3, 8); z3 += __shfl_xor(z3, 16); z3 += __shfl_xor(z3, 32);
    if ((t & 63) == 0) bsum[t >> 6] = z3;
  }
  __syncthreads();
  if (t == 0) atomicAdd(&acc[0], bsum[0] + bsum[1]);
}

// ---------------- finalize ------------------------------------------------
__global__ void fin_kernel(const float* __restrict__ acc, const float* __restrict__ regu2,
                           const float* __restrict__ regu, float* __restrict__ out) {
  if (threadIdx.x == 0)
    out[0] = acc[0] * (1.f / (float)NN) - regu2[0] * acc[1] - regu[0] * acc[2];
}

extern "C" void kernel_launch(void* const* d_in, const int* in_sizes, int n_in,
                              void* d_out, int out_size, void* d_ws, size_t ws_size,
                              hipStream_t stream) {
  const float* x     = (const float*)d_in[0];
  const float* W1    = (const float*)d_in[1];
  const float* W2    = (const float*)d_in[2];
  const float* W3    = (const float*)d_in[3];
  const float* regu2 = (const float*)d_in[4];
  const float* regu  = (const float*)d_in[5];
  const float* rlen  = (const float*)d_in[6];

  char* ws = (char*)d_ws;
  float* acc            = (float*)ws;                       // [0]=sum z3, [1]=sum x2, [2]=sum exp
  unsigned short* W1T   = (unsigned short*)(ws + 16);       // 64*8192 bf16 = 1 MB
  unsigned short* W2T   = (unsigned short*)(ws + 1048592);  // 64*64 bf16 = 8 KB
  float* part           = (float*)(ws + 1056784);           // 4*8192*64 f32 = 8 MB

  (void)hipMemsetAsync(acc, 0, 16, stream);
  prep_kernel<<<131, 256, 0, stream>>>(x, W1, W2, rlen, W1T, W2T, acc);
  main_kernel<<<1024, 256, 0, stream>>>(x, W1T, part);
  tail_kernel<<<64, 256, 0, stream>>>(part, W2T, W3, acc);
  fin_kernel<<<1, 64, 0, stream>>>(acc, regu2, regu, (float*)d_out);
}